// Round 1
// baseline (1152.541 us; speedup 1.0000x reference)
//
#include <hip/hip_runtime.h>
#include <math.h>

#define B_ 4
#define S_ 2048
#define D_ 1024
#define F_ 4096
#define E_ 4
#define T_ (B_*S_)   // 8192 tokens

typedef unsigned short ushort_t;
typedef __attribute__((ext_vector_type(8))) short short8;
typedef __attribute__((ext_vector_type(4))) float f32x4;

__device__ __forceinline__ ushort_t f2bf_rne(float f) {
    unsigned u = __float_as_uint(f);
    unsigned r = 0x7FFFu + ((u >> 16) & 1u);
    u += r;
    return (ushort_t)(u >> 16);
}
__device__ __forceinline__ float bf2f(ushort_t h) {
    return __uint_as_float(((unsigned)h) << 16);
}
__device__ __forceinline__ void split_bf16(float f, ushort_t &hi, ushort_t &lo) {
    hi = f2bf_rne(f);
    lo = f2bf_rne(f - bf2f(hi));
}

// K1: r[t][e] = x[t,:] . rw[:,e]   (one wave per token) ; block 0 zeroes counts
__global__ void k_router(const float* __restrict__ x, const float* __restrict__ rw,
                         float* __restrict__ r, int* __restrict__ counts) {
    if (blockIdx.x == 0 && threadIdx.x < E_) counts[threadIdx.x] = 0;
    int wid = blockIdx.x * 4 + (threadIdx.x >> 6);
    int lane = threadIdx.x & 63;
    const float* xr = x + (size_t)wid * D_;
    float a0 = 0.f, a1 = 0.f, a2 = 0.f, a3 = 0.f;
    for (int i = lane; i < D_; i += 64) {
        float xv = xr[i];
        float4 w = reinterpret_cast<const float4*>(rw)[i];
        a0 += xv * w.x; a1 += xv * w.y; a2 += xv * w.z; a3 += xv * w.w;
    }
    for (int off = 32; off; off >>= 1) {
        a0 += __shfl_down(a0, off, 64);
        a1 += __shfl_down(a1, off, 64);
        a2 += __shfl_down(a2, off, 64);
        a3 += __shfl_down(a3, off, 64);
    }
    if (lane == 0) {
        float4 v; v.x = a0; v.y = a1; v.z = a2; v.w = a3;
        reinterpret_cast<float4*>(r)[wid] = v;
    }
}

// K2a: in-place inclusive cumsum over s for each (b,e). One wave per (b,e).
__global__ void k_scan(float* __restrict__ r) {
    int b = blockIdx.x >> 2, e = blockIdx.x & 3;
    int lane = threadIdx.x;
    float carry = 0.f;
    for (int c = 0; c < S_ / 64; ++c) {
        int s = c * 64 + lane;
        float* p = r + ((size_t)(b * S_ + s)) * E_ + e;
        float v = *p;
        #pragma unroll
        for (int off = 1; off < 64; off <<= 1) {
            float u = __shfl_up(v, off, 64);
            if (lane >= off) v += u;
        }
        v += carry;
        *p = v;
        carry = __shfl(v, 63, 64);
    }
}

// K2b: softmax over E, argmax (first max), gate = 1/sum(exp(l-lmax)), expert lists
__global__ void k_route(const float* __restrict__ r, float* __restrict__ gate,
                        int* __restrict__ list, int* __restrict__ counts) {
    int t = blockIdx.x * blockDim.x + threadIdx.x;
    if (t >= T_) return;
    int s = t & (S_ - 1);
    float4 l4 = reinterpret_cast<const float4*>(r)[t];
    float inv = 1.f / (float)(s + 1);
    float l[4] = { l4.x * inv, l4.y * inv, l4.z * inv, l4.w * inv };
    int best = 0; float m = l[0];
    #pragma unroll
    for (int e = 1; e < 4; ++e) if (l[e] > m) { m = l[e]; best = e; }
    float sum = 0.f;
    #pragma unroll
    for (int e = 0; e < 4; ++e) sum += expf(l[e] - m);
    gate[t] = 1.f / sum;
    int pos = atomicAdd(&counts[best], 1);
    list[best * T_ + pos] = t;
}

// Grouped GEMM over one expert's token list, split-bf16 3-pass MFMA.
// MODE 0: C = gelu(A@We + bias)  (A=x, K=D, N=F, C=h)
// MODE 1: C = gate * (A@We + bias)  (A=h, K=F, N=D, C=out)
// Block: 256 thr, tile 64(M) x 128(N), BK=32. 4 waves, each 32x64.
template<int MODE>
__global__ __launch_bounds__(256)
void k_gemm(const float* __restrict__ A, const float* __restrict__ W,
            const float* __restrict__ bias, float* __restrict__ C,
            const int* __restrict__ list, const int* __restrict__ counts,
            const float* __restrict__ gate, int K, int N)
{
    const int e = blockIdx.z;
    const int cnt = counts[e];
    const int m0 = blockIdx.x * 64;
    if (m0 >= cnt) return;
    const int n0 = blockIdx.y * 128;
    const float* We = W + (size_t)e * K * N;
    const float* be = bias + (size_t)e * N;
    const int* lst = list + (size_t)e * T_;

    const int tid = threadIdx.x;
    const int wid = tid >> 6;
    const int lane = tid & 63;

    // fragment-order LDS: A_hi[4rf][64lane][8] @0, A_lo @2048, B_hi[8nt][64][8] @4096, B_lo @8192
    __shared__ __align__(16) ushort_t lds[12288];

    // A staging: row = tid>>2 (0..63), kseg = (tid&3)*8
    const int arow = tid >> 2;
    const int akseg = (tid & 3) * 8;
    const int am = m0 + arow;
    const int at = (am < cnt) ? lst[am] : -1;
    const float* aptr = A + (size_t)(at >= 0 ? at : 0) * K;
    const int a_lds = (arow >> 4) * 512 + ((akseg >> 3) * 16 + (arow & 15)) * 8;

    // B staging: col = tid&127, kb = (tid>>7)*16 ; 2 runs of 8 k each
    const int bcol = tid & 127;
    const int bkb = (tid >> 7) * 16;
    const int bnt = bcol >> 4;
    const int bc15 = bcol & 15;

    const int wr = wid >> 1;  // row half (rows wr*32..)
    const int wc = wid & 1;   // col half (cols wc*64..)

    f32x4 acc[2][4];
    #pragma unroll
    for (int i = 0; i < 2; ++i)
        #pragma unroll
        for (int j = 0; j < 4; ++j) acc[i][j] = (f32x4){0.f, 0.f, 0.f, 0.f};

    for (int k0 = 0; k0 < K; k0 += 32) {
        __syncthreads();
        // ---- stage A (64x32 fp32 -> hi/lo bf16, fragment order) ----
        {
            float v[8];
            if (at >= 0) {
                float4 u0 = *reinterpret_cast<const float4*>(aptr + k0 + akseg);
                float4 u1 = *reinterpret_cast<const float4*>(aptr + k0 + akseg + 4);
                v[0] = u0.x; v[1] = u0.y; v[2] = u0.z; v[3] = u0.w;
                v[4] = u1.x; v[5] = u1.y; v[6] = u1.z; v[7] = u1.w;
            } else {
                #pragma unroll
                for (int j = 0; j < 8; ++j) v[j] = 0.f;
            }
            unsigned hiw[4], low[4];
            #pragma unroll
            for (int j = 0; j < 4; ++j) {
                ushort_t h0, l0, h1, l1;
                split_bf16(v[2*j], h0, l0);
                split_bf16(v[2*j+1], h1, l1);
                hiw[j] = (unsigned)h0 | ((unsigned)h1 << 16);
                low[j] = (unsigned)l0 | ((unsigned)l1 << 16);
            }
            *reinterpret_cast<uint4*>(&lds[a_lds])        = make_uint4(hiw[0], hiw[1], hiw[2], hiw[3]);
            *reinterpret_cast<uint4*>(&lds[2048 + a_lds]) = make_uint4(low[0], low[1], low[2], low[3]);
        }
        // ---- stage B (32x128 fp32 -> hi/lo bf16, fragment order) ----
        {
            #pragma unroll
            for (int h8 = 0; h8 < 16; h8 += 8) {
                unsigned hiw[4], low[4];
                #pragma unroll
                for (int j = 0; j < 8; j += 2) {
                    float f0 = We[(size_t)(k0 + bkb + h8 + j)     * N + n0 + bcol];
                    float f1 = We[(size_t)(k0 + bkb + h8 + j + 1) * N + n0 + bcol];
                    ushort_t h0, l0, h1, l1;
                    split_bf16(f0, h0, l0);
                    split_bf16(f1, h1, l1);
                    hiw[j >> 1] = (unsigned)h0 | ((unsigned)h1 << 16);
                    low[j >> 1] = (unsigned)l0 | ((unsigned)l1 << 16);
                }
                int g = (bkb + h8) >> 3;
                int base = bnt * 512 + (g * 16 + bc15) * 8;
                *reinterpret_cast<uint4*>(&lds[4096 + base]) = make_uint4(hiw[0], hiw[1], hiw[2], hiw[3]);
                *reinterpret_cast<uint4*>(&lds[8192 + base]) = make_uint4(low[0], low[1], low[2], low[3]);
            }
        }
        __syncthreads();
        // ---- fragments + MFMA (3-pass split) ----
        short8 ah[2], al[2], bh[4], bl[4];
        #pragma unroll
        for (int mi = 0; mi < 2; ++mi) {
            int rf = wr * 2 + mi;
            ah[mi] = *reinterpret_cast<const short8*>(&lds[rf * 512 + lane * 8]);
            al[mi] = *reinterpret_cast<const short8*>(&lds[2048 + rf * 512 + lane * 8]);
        }
        #pragma unroll
        for (int ni = 0; ni < 4; ++ni) {
            int nt = wc * 4 + ni;
            bh[ni] = *reinterpret_cast<const short8*>(&lds[4096 + nt * 512 + lane * 8]);
            bl[ni] = *reinterpret_cast<const short8*>(&lds[8192 + nt * 512 + lane * 8]);
        }
        #pragma unroll
        for (int mi = 0; mi < 2; ++mi)
            #pragma unroll
            for (int ni = 0; ni < 4; ++ni) {
                acc[mi][ni] = __builtin_amdgcn_mfma_f32_16x16x32_bf16(ah[mi], bh[ni], acc[mi][ni], 0, 0, 0);
                acc[mi][ni] = __builtin_amdgcn_mfma_f32_16x16x32_bf16(ah[mi], bl[ni], acc[mi][ni], 0, 0, 0);
                acc[mi][ni] = __builtin_amdgcn_mfma_f32_16x16x32_bf16(al[mi], bh[ni], acc[mi][ni], 0, 0, 0);
            }
    }

    // ---- epilogue: C frag layout col=lane&15, row=(lane>>4)*4+reg ----
    const int colbase = n0 + wc * 64 + (lane & 15);
    const int rowq = (lane >> 4) * 4;
    #pragma unroll
    for (int mi = 0; mi < 2; ++mi) {
        #pragma unroll
        for (int rg = 0; rg < 4; ++rg) {
            int rm = m0 + wr * 32 + mi * 16 + rowq + rg;
            if (rm >= cnt) continue;
            int t = lst[rm];
            float gv = (MODE == 1) ? gate[t] : 0.f;
            float* crow = C + (size_t)t * N;
            #pragma unroll
            for (int ni = 0; ni < 4; ++ni) {
                int col = colbase + ni * 16;
                float v = acc[mi][ni][rg] + be[col];
                if (MODE == 0) {
                    float u = 0.7978845608028654f * (v + 0.044715f * v * v * v);
                    v = 0.5f * v * (1.f + tanhf(u));
                } else {
                    v *= gv;
                }
                crow[col] = v;
            }
        }
    }
}

extern "C" void kernel_launch(void* const* d_in, const int* in_sizes, int n_in,
                              void* d_out, int out_size, void* d_ws, size_t ws_size,
                              hipStream_t stream) {
    const float* x   = (const float*)d_in[0];
    const float* rw  = (const float*)d_in[1];
    const float* w1  = (const float*)d_in[2];
    const float* b1  = (const float*)d_in[3];
    const float* w2  = (const float*)d_in[4];
    const float* b2  = (const float*)d_in[5];
    float* out = (float*)d_out;

    // workspace layout
    const size_t h_elems = (size_t)T_ * F_;
    const size_t need = h_elems * 4            // h fp32
                      + (size_t)T_ * E_ * 4    // r / cums
                      + (size_t)T_ * 4         // gate
                      + (size_t)E_ * T_ * 4    // lists
                      + E_ * 4;                // counts
    if (ws_size < need) return;  // ws too small -> leave poison, fail loudly

    float* h    = (float*)d_ws;
    float* r    = h + h_elems;
    float* gate = r + (size_t)T_ * E_;
    int* list   = (int*)(gate + T_);
    int* counts = list + (size_t)E_ * T_;

    k_router<<<T_ / 4, 256, 0, stream>>>(x, rw, r, counts);
    k_scan<<<B_ * E_, 64, 0, stream>>>(r);
    k_route<<<T_ / 256, 256, 0, stream>>>(r, gate, list, counts);

    dim3 g1(T_ / 64, F_ / 128, E_);
    k_gemm<0><<<g1, 256, 0, stream>>>(x, w1, b1, h, list, counts, nullptr, D_, F_);
    dim3 g2(T_ / 64, D_ / 128, E_);
    k_gemm<1><<<g2, 256, 0, stream>>>(h, w2, b2, out, list, counts, gate, F_, D_);
}

// Round 2
// 1141.021 us; speedup vs baseline: 1.0101x; 1.0101x over previous
//
#include <hip/hip_runtime.h>
#include <math.h>

#define B_ 4
#define S_ 2048
#define D_ 1024
#define F_ 4096
#define E_ 4
#define T_ (B_*S_)   // 8192 tokens

typedef unsigned short ushort_t;
typedef __attribute__((ext_vector_type(8))) short short8;
typedef __attribute__((ext_vector_type(4))) float f32x4;

__device__ __forceinline__ ushort_t f2bf_rne(float f) {
    unsigned u = __float_as_uint(f);
    unsigned r = 0x7FFFu + ((u >> 16) & 1u);
    u += r;
    return (ushort_t)(u >> 16);
}
__device__ __forceinline__ float bf2f(ushort_t h) {
    return __uint_as_float(((unsigned)h) << 16);
}
__device__ __forceinline__ void split_bf16(float f, ushort_t &hi, ushort_t &lo) {
    hi = f2bf_rne(f);
    lo = f2bf_rne(f - bf2f(hi));
}

__device__ __forceinline__ void gload16(const void* g, void* l) {
    __builtin_amdgcn_global_load_lds(
        (const __attribute__((address_space(1))) unsigned int*)g,
        (__attribute__((address_space(3))) unsigned int*)l, 16, 0, 0);
}

// ---------------- routing ----------------

__global__ void k_router(const float* __restrict__ x, const float* __restrict__ rw,
                         float* __restrict__ r, int* __restrict__ counts) {
    if (blockIdx.x == 0 && threadIdx.x < E_) counts[threadIdx.x] = 0;
    int wid = blockIdx.x * 4 + (threadIdx.x >> 6);
    int lane = threadIdx.x & 63;
    const float* xr = x + (size_t)wid * D_;
    float a0 = 0.f, a1 = 0.f, a2 = 0.f, a3 = 0.f;
    for (int i = lane; i < D_; i += 64) {
        float xv = xr[i];
        float4 w = reinterpret_cast<const float4*>(rw)[i];
        a0 += xv * w.x; a1 += xv * w.y; a2 += xv * w.z; a3 += xv * w.w;
    }
    for (int off = 32; off; off >>= 1) {
        a0 += __shfl_down(a0, off, 64);
        a1 += __shfl_down(a1, off, 64);
        a2 += __shfl_down(a2, off, 64);
        a3 += __shfl_down(a3, off, 64);
    }
    if (lane == 0) {
        float4 v; v.x = a0; v.y = a1; v.z = a2; v.w = a3;
        reinterpret_cast<float4*>(r)[wid] = v;
    }
}

__global__ void k_scan(float* __restrict__ r) {
    int b = blockIdx.x >> 2, e = blockIdx.x & 3;
    int lane = threadIdx.x;
    float carry = 0.f;
    for (int c = 0; c < S_ / 64; ++c) {
        int s = c * 64 + lane;
        float* p = r + ((size_t)(b * S_ + s)) * E_ + e;
        float v = *p;
        #pragma unroll
        for (int off = 1; off < 64; off <<= 1) {
            float u = __shfl_up(v, off, 64);
            if (lane >= off) v += u;
        }
        v += carry;
        *p = v;
        carry = __shfl(v, 63, 64);
    }
}

__global__ void k_route(const float* __restrict__ r, float* __restrict__ gate,
                        int* __restrict__ list, int* __restrict__ counts) {
    int t = blockIdx.x * blockDim.x + threadIdx.x;
    if (t >= T_) return;
    int s = t & (S_ - 1);
    float4 l4 = reinterpret_cast<const float4*>(r)[t];
    float inv = 1.f / (float)(s + 1);
    float l[4] = { l4.x * inv, l4.y * inv, l4.z * inv, l4.w * inv };
    int best = 0; float m = l[0];
    #pragma unroll
    for (int e = 1; e < 4; ++e) if (l[e] > m) { m = l[e]; best = e; }
    float sum = 0.f;
    #pragma unroll
    for (int e = 0; e < 4; ++e) sum += expf(l[e] - m);
    gate[t] = 1.f / sum;
    int pos = atomicAdd(&counts[best], 1);
    list[best * T_ + pos] = t;
}

__global__ void k_offs(const int* __restrict__ counts, int* __restrict__ offs) {
    if (threadIdx.x == 0) {
        int a = 0;
        for (int e = 0; e < E_; ++e) { offs[e] = a; a += counts[e]; }
    }
}

// ---------------- pre-conversion ----------------

// x -> hi/lo bf16 planes, row-major [T][D]
__global__ void k_convert_x(const float* __restrict__ x,
                            ushort_t* __restrict__ xh, ushort_t* __restrict__ xl) {
    size_t i = ((size_t)blockIdx.x * 256 + threadIdx.x) * 8;
    float4 a = *reinterpret_cast<const float4*>(x + i);
    float4 b = *reinterpret_cast<const float4*>(x + i + 4);
    float v[8] = { a.x, a.y, a.z, a.w, b.x, b.y, b.z, b.w };
    unsigned hw[4], lw[4];
    #pragma unroll
    for (int j = 0; j < 4; ++j) {
        ushort_t h0, l0, h1, l1;
        split_bf16(v[2*j], h0, l0);
        split_bf16(v[2*j+1], h1, l1);
        hw[j] = (unsigned)h0 | ((unsigned)h1 << 16);
        lw[j] = (unsigned)l0 | ((unsigned)l1 << 16);
    }
    *reinterpret_cast<uint4*>(xh + i) = make_uint4(hw[0], hw[1], hw[2], hw[3]);
    *reinterpret_cast<uint4*>(xl + i) = make_uint4(lw[0], lw[1], lw[2], lw[3]);
}

// W [e][K][N] fp32 -> frag-order planes [e][nt][kb][64][8] hi / lo.
// grid: (N/128, K/32, E), 256 threads.
__global__ __launch_bounds__(256)
void k_convert_w(const float* __restrict__ W, ushort_t* __restrict__ Ph,
                 ushort_t* __restrict__ Pl, int K, int N) {
    const int e = blockIdx.z;
    const int n0 = blockIdx.x * 128;
    const int k0 = blockIdx.y * 32;
    const int kb = blockIdx.y;
    const int NT = N >> 4, KB = K >> 5;
    __shared__ float lf[32 * 128];
    const float* We = W + (size_t)e * K * N;
    const int tid = threadIdx.x;
    #pragma unroll
    for (int i = 0; i < 4; ++i) {
        int q = i * 256 + tid;            // 0..1023
        int k = q >> 5, c4 = q & 31;
        float4 v = *reinterpret_cast<const float4*>(We + (size_t)(k0 + k) * N + n0 + c4 * 4);
        *reinterpret_cast<float4*>(lf + k * 128 + c4 * 4) = v;
    }
    __syncthreads();
    #pragma unroll
    for (int p = 0; p < 2; ++p) {
        int q = p * 256 + tid;            // 0..511
        int n = q & 127, kg = q >> 7;
        unsigned hw[4], lw[4];
        #pragma unroll
        for (int j = 0; j < 8; j += 2) {
            float f0 = lf[(kg * 8 + j) * 128 + n];
            float f1 = lf[(kg * 8 + j + 1) * 128 + n];
            ushort_t h0, l0, h1, l1;
            split_bf16(f0, h0, l0);
            split_bf16(f1, h1, l1);
            hw[j >> 1] = (unsigned)h0 | ((unsigned)h1 << 16);
            lw[j >> 1] = (unsigned)l0 | ((unsigned)l1 << 16);
        }
        size_t off = ((((size_t)e * NT + ((n0 + n) >> 4)) * KB + kb) * 64
                      + (kg * 16 + (n & 15))) * 8;
        *reinterpret_cast<uint4*>(Ph + off) = make_uint4(hw[0], hw[1], hw[2], hw[3]);
        *reinterpret_cast<uint4*>(Pl + off) = make_uint4(lw[0], lw[1], lw[2], lw[3]);
    }
}

// ---------------- main GEMMs (pre-converted, global_load_lds) ----------------
// MODE 0: C = gelu(A@B + b1) -> h planes (expert-local rows). A = x planes (gather via list).
// MODE 1: C = gate * (A@B + b2) -> out fp32 (scatter via list). A = h planes (contiguous).
// Tile 128x128, BK=32, 4 waves (2x2), wave tile 64x64.
template<int MODE>
__global__ __launch_bounds__(256)
void k_gemm2(const ushort_t* __restrict__ Ah, const ushort_t* __restrict__ Al,
             const ushort_t* __restrict__ Bh, const ushort_t* __restrict__ Bl,
             const float* __restrict__ bias, float* __restrict__ outF,
             ushort_t* __restrict__ outHh, ushort_t* __restrict__ outHl,
             const int* __restrict__ list, const int* __restrict__ counts,
             const int* __restrict__ offs, const float* __restrict__ gate,
             int K, int N, int NT)
{
    const int e = blockIdx.z;
    const int cnt = counts[e];
    const int m0 = blockIdx.x * 128;
    if (m0 >= cnt) return;
    const int n0 = blockIdx.y * 128;
    const int hbase = offs[e];
    const int KB = K >> 5;
    const int tid = threadIdx.x, wid = tid >> 6, lane = tid & 63;
    const int l15 = lane & 15, lkg = lane >> 4;
    const int* lst = list + (size_t)e * T_;

    // Ah[8][512] @0, Al @4096, Bh @8192, Bl @12288 (ushort offsets)
    __shared__ __align__(16) ushort_t lds[16384];

    size_t a_rel[2], b_rel[2];
    #pragma unroll
    for (int i = 0; i < 2; ++i) {
        int rf = wid * 2 + i;
        int rm = m0 + rf * 16 + l15;
        int rr = rm < cnt ? rm : cnt - 1;
        size_t row = (MODE == 0) ? (size_t)lst[rr] : (size_t)(hbase + rr);
        a_rel[i] = row * (size_t)K + (size_t)lkg * 8;
        b_rel[i] = (((size_t)e * NT + (n0 >> 4) + rf) * (size_t)KB) * 512 + (size_t)lane * 8;
    }
    const int wr = wid >> 1, wc = wid & 1;

    f32x4 acc[4][4];
    #pragma unroll
    for (int i = 0; i < 4; ++i)
        #pragma unroll
        for (int j = 0; j < 4; ++j) acc[i][j] = (f32x4){0.f, 0.f, 0.f, 0.f};

    for (int kb = 0; kb < KB; ++kb) {
        __syncthreads();
        #pragma unroll
        for (int i = 0; i < 2; ++i) {
            int c = wid * 2 + i;
            gload16(Ah + a_rel[i] + (size_t)kb * 32, &lds[c * 512]);
            gload16(Al + a_rel[i] + (size_t)kb * 32, &lds[4096 + c * 512]);
            gload16(Bh + b_rel[i] + (size_t)kb * 512, &lds[8192 + c * 512]);
            gload16(Bl + b_rel[i] + (size_t)kb * 512, &lds[12288 + c * 512]);
        }
        __syncthreads();
        short8 ah[4], al[4], bh[4], bl[4];
        #pragma unroll
        for (int mi = 0; mi < 4; ++mi) {
            int rf = wr * 4 + mi;
            ah[mi] = *reinterpret_cast<const short8*>(&lds[rf * 512 + lane * 8]);
            al[mi] = *reinterpret_cast<const short8*>(&lds[4096 + rf * 512 + lane * 8]);
        }
        #pragma unroll
        for (int ni = 0; ni < 4; ++ni) {
            int nt = wc * 4 + ni;
            bh[ni] = *reinterpret_cast<const short8*>(&lds[8192 + nt * 512 + lane * 8]);
            bl[ni] = *reinterpret_cast<const short8*>(&lds[12288 + nt * 512 + lane * 8]);
        }
        #pragma unroll
        for (int mi = 0; mi < 4; ++mi)
            #pragma unroll
            for (int ni = 0; ni < 4; ++ni) {
                acc[mi][ni] = __builtin_amdgcn_mfma_f32_16x16x32_bf16(ah[mi], bh[ni], acc[mi][ni], 0, 0, 0);
                acc[mi][ni] = __builtin_amdgcn_mfma_f32_16x16x32_bf16(ah[mi], bl[ni], acc[mi][ni], 0, 0, 0);
                acc[mi][ni] = __builtin_amdgcn_mfma_f32_16x16x32_bf16(al[mi], bh[ni], acc[mi][ni], 0, 0, 0);
            }
    }

    const float* be = bias + (size_t)e * N;
    #pragma unroll
    for (int mi = 0; mi < 4; ++mi) {
        #pragma unroll
        for (int rg = 0; rg < 4; ++rg) {
            int rm = m0 + wr * 64 + mi * 16 + lkg * 4 + rg;
            if (rm >= cnt) continue;
            if (MODE == 0) {
                size_t rowb = (size_t)(hbase + rm) * (size_t)F_;
                #pragma unroll
                for (int ni = 0; ni < 4; ++ni) {
                    int col = n0 + wc * 64 + ni * 16 + l15;
                    float v = acc[mi][ni][rg] + be[col];
                    // gelu(v) = v * sigmoid(2*sqrt(2/pi)*(v+0.044715v^3))
                    float u = 1.5957691216057308f * (v + 0.044715f * v * v * v);
                    v = v / (1.f + __expf(-u));
                    ushort_t h, l;
                    split_bf16(v, h, l);
                    outHh[rowb + col] = h;
                    outHl[rowb + col] = l;
                }
            } else {
                int t = lst[rm];
                float gv = gate[t];
                float* crow = outF + (size_t)t * (size_t)N;
                #pragma unroll
                for (int ni = 0; ni < 4; ++ni) {
                    int col = n0 + wc * 64 + ni * 16 + l15;
                    crow[col] = gv * (acc[mi][ni][rg] + be[col]);
                }
            }
        }
    }
}

// ---------------- fallback (round-1 kernel, used if ws too small) ----------------
template<int MODE>
__global__ __launch_bounds__(256)
void k_gemm_fb(const float* __restrict__ A, const float* __restrict__ W,
               const float* __restrict__ bias, float* __restrict__ C,
               const int* __restrict__ list, const int* __restrict__ counts,
               const float* __restrict__ gate, int K, int N)
{
    const int e = blockIdx.z;
    const int cnt = counts[e];
    const int m0 = blockIdx.x * 64;
    if (m0 >= cnt) return;
    const int n0 = blockIdx.y * 128;
    const float* We = W + (size_t)e * K * N;
    const float* be = bias + (size_t)e * N;
    const int* lst = list + (size_t)e * T_;
    const int tid = threadIdx.x;
    const int wid = tid >> 6;
    const int lane = tid & 63;
    __shared__ __align__(16) ushort_t lds[12288];
    const int arow = tid >> 2;
    const int akseg = (tid & 3) * 8;
    const int am = m0 + arow;
    const int at = (am < cnt) ? lst[am] : -1;
    const float* aptr = A + (size_t)(at >= 0 ? at : 0) * K;
    const int a_lds = (arow >> 4) * 512 + ((akseg >> 3) * 16 + (arow & 15)) * 8;
    const int bcol = tid & 127;
    const int bkb = (tid >> 7) * 16;
    const int bnt = bcol >> 4;
    const int bc15 = bcol & 15;
    const int wr = wid >> 1;
    const int wc = wid & 1;
    f32x4 acc[2][4];
    #pragma unroll
    for (int i = 0; i < 2; ++i)
        #pragma unroll
        for (int j = 0; j < 4; ++j) acc[i][j] = (f32x4){0.f, 0.f, 0.f, 0.f};
    for (int k0 = 0; k0 < K; k0 += 32) {
        __syncthreads();
        {
            float v[8];
            if (at >= 0) {
                float4 u0 = *reinterpret_cast<const float4*>(aptr + k0 + akseg);
                float4 u1 = *reinterpret_cast<const float4*>(aptr + k0 + akseg + 4);
                v[0] = u0.x; v[1] = u0.y; v[2] = u0.z; v[3] = u0.w;
                v[4] = u1.x; v[5] = u1.y; v[6] = u1.z; v[7] = u1.w;
            } else {
                #pragma unroll
                for (int j = 0; j < 8; ++j) v[j] = 0.f;
            }
            unsigned hiw[4], low[4];
            #pragma unroll
            for (int j = 0; j < 4; ++j) {
                ushort_t h0, l0, h1, l1;
                split_bf16(v[2*j], h0, l0);
                split_bf16(v[2*j+1], h1, l1);
                hiw[j] = (unsigned)h0 | ((unsigned)h1 << 16);
                low[j] = (unsigned)l0 | ((unsigned)l1 << 16);
            }
            *reinterpret_cast<uint4*>(&lds[a_lds])        = make_uint4(hiw[0], hiw[1], hiw[2], hiw[3]);
            *reinterpret_cast<uint4*>(&lds[2048 + a_lds]) = make_uint4(low[0], low[1], low[2], low[3]);
        }
        {
            #pragma unroll
            for (int h8 = 0; h8 < 16; h8 += 8) {
                unsigned hiw[4], low[4];
                #pragma unroll
                for (int j = 0; j < 8; j += 2) {
                    float f0 = We[(size_t)(k0 + bkb + h8 + j)     * N + n0 + bcol];
                    float f1 = We[(size_t)(k0 + bkb + h8 + j + 1) * N + n0 + bcol];
                    ushort_t h0, l0, h1, l1;
                    split_bf16(f0, h0, l0);
                    split_bf16(f1, h1, l1);
                    hiw[j >> 1] = (unsigned)h0 | ((unsigned)h1 << 16);
                    low[j >> 1] = (unsigned)l0 | ((unsigned)l1 << 16);
                }
                int g = (bkb + h8) >> 3;
                int base = bnt * 512 + (g * 16 + bc15) * 8;
                *reinterpret_cast<uint4*>(&lds[4096 + base]) = make_uint4(hiw[0], hiw[1], hiw[2], hiw[3]);
                *reinterpret_cast<uint4*>(&lds[8192 + base]) = make_uint4(low[0], low[1], low[2], low[3]);
            }
        }
        __syncthreads();
        short8 ah[2], al[2], bh[4], bl[4];
        #pragma unroll
        for (int mi = 0; mi < 2; ++mi) {
            int rf = wr * 2 + mi;
            ah[mi] = *reinterpret_cast<const short8*>(&lds[rf * 512 + lane * 8]);
            al[mi] = *reinterpret_cast<const short8*>(&lds[2048 + rf * 512 + lane * 8]);
        }
        #pragma unroll
        for (int ni = 0; ni < 4; ++ni) {
            int nt = wc * 4 + ni;
            bh[ni] = *reinterpret_cast<const short8*>(&lds[4096 + nt * 512 + lane * 8]);
            bl[ni] = *reinterpret_cast<const short8*>(&lds[8192 + nt * 512 + lane * 8]);
        }
        #pragma unroll
        for (int mi = 0; mi < 2; ++mi)
            #pragma unroll
            for (int ni = 0; ni < 4; ++ni) {
                acc[mi][ni] = __builtin_amdgcn_mfma_f32_16x16x32_bf16(ah[mi], bh[ni], acc[mi][ni], 0, 0, 0);
                acc[mi][ni] = __builtin_amdgcn_mfma_f32_16x16x32_bf16(ah[mi], bl[ni], acc[mi][ni], 0, 0, 0);
                acc[mi][ni] = __builtin_amdgcn_mfma_f32_16x16x32_bf16(al[mi], bh[ni], acc[mi][ni], 0, 0, 0);
            }
    }
    const int colbase = n0 + wc * 64 + (lane & 15);
    const int rowq = (lane >> 4) * 4;
    #pragma unroll
    for (int mi = 0; mi < 2; ++mi) {
        #pragma unroll
        for (int rg = 0; rg < 4; ++rg) {
            int rm = m0 + wr * 32 + mi * 16 + rowq + rg;
            if (rm >= cnt) continue;
            int t = lst[rm];
            float gv = (MODE == 1) ? gate[t] : 0.f;
            float* crow = C + (size_t)t * N;
            #pragma unroll
            for (int ni = 0; ni < 4; ++ni) {
                int col = colbase + ni * 16;
                float v = acc[mi][ni][rg] + be[col];
                if (MODE == 0) {
                    float u = 1.5957691216057308f * (v + 0.044715f * v * v * v);
                    v = v / (1.f + __expf(-u));
                } else {
                    v *= gv;
                }
                crow[col] = v;
            }
        }
    }
}

// ---------------- launch ----------------

extern "C" void kernel_launch(void* const* d_in, const int* in_sizes, int n_in,
                              void* d_out, int out_size, void* d_ws, size_t ws_size,
                              hipStream_t stream) {
    const float* x   = (const float*)d_in[0];
    const float* rw  = (const float*)d_in[1];
    const float* w1  = (const float*)d_in[2];
    const float* b1  = (const float*)d_in[3];
    const float* w2  = (const float*)d_in[4];
    const float* b2  = (const float*)d_in[5];
    float* out = (float*)d_out;

    const size_t hf = (size_t)T_ * F_;          // 33.55M elems
    const size_t xd = (size_t)T_ * D_;          // 8.39M
    const size_t wsz = (size_t)E_ * D_ * F_;    // 16.78M

    const size_t need_full = hf * 2 * 2 + xd * 2 * 2 + wsz * 2 * 2
                           + (size_t)T_ * E_ * 4 + (size_t)T_ * 4
                           + (size_t)E_ * T_ * 4 + 64;
    const size_t need_fb   = hf * 4 + (size_t)T_ * E_ * 4 + (size_t)T_ * 4
                           + (size_t)E_ * T_ * 4 + 64;

    if (ws_size >= need_full) {
        ushort_t* hh  = (ushort_t*)d_ws;
        ushort_t* hl  = hh + hf;
        ushort_t* xh  = hl + hf;
        ushort_t* xl  = xh + xd;
        ushort_t* wph = xl + xd;
        ushort_t* wpl = wph + wsz;
        float* r    = (float*)(wpl + wsz);
        float* gate = r + (size_t)T_ * E_;
        int* list   = (int*)(gate + T_);
        int* counts = list + (size_t)E_ * T_;
        int* offs   = counts + E_;

        k_router<<<T_ / 4, 256, 0, stream>>>(x, rw, r, counts);
        k_convert_x<<<(int)(xd / 2048), 256, 0, stream>>>(x, xh, xl);
        k_convert_w<<<dim3(F_ / 128, D_ / 32, E_), 256, 0, stream>>>(w1, wph, wpl, D_, F_);
        k_scan<<<B_ * E_, 64, 0, stream>>>(r);
        k_route<<<T_ / 256, 256, 0, stream>>>(r, gate, list, counts);
        k_offs<<<1, 64, 0, stream>>>(counts, offs);

        k_gemm2<0><<<dim3(T_ / 128, F_ / 128, E_), 256, 0, stream>>>(
            xh, xl, wph, wpl, b1, nullptr, hh, hl, list, counts, offs, nullptr,
            D_, F_, F_ / 16);
        k_convert_w<<<dim3(D_ / 128, F_ / 32, E_), 256, 0, stream>>>(w2, wph, wpl, F_, D_);
        k_gemm2<1><<<dim3(T_ / 128, D_ / 128, E_), 256, 0, stream>>>(
            hh, hl, wph, wpl, b2, out, nullptr, nullptr, list, counts, offs, gate,
            F_, D_, D_ / 16);
    } else if (ws_size >= need_fb) {
        float* h    = (float*)d_ws;
        float* r    = h + hf;
        float* gate = r + (size_t)T_ * E_;
        int* list   = (int*)(gate + T_);
        int* counts = list + (size_t)E_ * T_;

        k_router<<<T_ / 4, 256, 0, stream>>>(x, rw, r, counts);
        k_scan<<<B_ * E_, 64, 0, stream>>>(r);
        k_route<<<T_ / 256, 256, 0, stream>>>(r, gate, list, counts);

        dim3 g1(T_ / 64, F_ / 128, E_);
        k_gemm_fb<0><<<g1, 256, 0, stream>>>(x, w1, b1, h, list, counts, nullptr, D_, F_);
        dim3 g2(T_ / 64, D_ / 128, E_);
        k_gemm_fb<1><<<g2, 256, 0, stream>>>(h, w2, b2, out, list, counts, gate, F_, D_);
    }
    // else: ws too small -> leave poison, fail loudly
}

// Round 3
// 1105.740 us; speedup vs baseline: 1.0423x; 1.0319x over previous
//
#include <hip/hip_runtime.h>
#include <math.h>

#define B_ 4
#define S_ 2048
#define D_ 1024
#define F_ 4096
#define E_ 4
#define T_ (B_*S_)        // 8192 tokens
#define PCAP_ 8704        // max padded rows: 8192 + 4*127 rounded to 128
#define GCAP_ (PCAP_/16)  // 544 row-groups

typedef unsigned short ushort_t;
typedef __attribute__((ext_vector_type(8))) short short8;
typedef __attribute__((ext_vector_type(4))) float f32x4;

__device__ __forceinline__ ushort_t f2bf_rne(float f) {
    unsigned u = __float_as_uint(f);
    unsigned r = 0x7FFFu + ((u >> 16) & 1u);
    u += r;
    return (ushort_t)(u >> 16);
}
__device__ __forceinline__ float bf2f(ushort_t h) {
    return __uint_as_float(((unsigned)h) << 16);
}
__device__ __forceinline__ void split_bf16(float f, ushort_t &hi, ushort_t &lo) {
    hi = f2bf_rne(f);
    lo = f2bf_rne(f - bf2f(hi));
}

__device__ __forceinline__ void gload16(const void* g, void* l) {
    __builtin_amdgcn_global_load_lds(
        (const __attribute__((address_space(1))) unsigned int*)g,
        (__attribute__((address_space(3))) unsigned int*)l, 16, 0, 0);
}

// ---------------- routing ----------------

__global__ void k_router(const float* __restrict__ x, const float* __restrict__ rw,
                         float* __restrict__ r, int* __restrict__ counts) {
    if (blockIdx.x == 0 && threadIdx.x < E_) counts[threadIdx.x] = 0;
    int wid = blockIdx.x * 4 + (threadIdx.x >> 6);
    int lane = threadIdx.x & 63;
    const float* xr = x + (size_t)wid * D_;
    float a0 = 0.f, a1 = 0.f, a2 = 0.f, a3 = 0.f;
    for (int i = lane; i < D_; i += 64) {
        float xv = xr[i];
        float4 w = reinterpret_cast<const float4*>(rw)[i];
        a0 += xv * w.x; a1 += xv * w.y; a2 += xv * w.z; a3 += xv * w.w;
    }
    for (int off = 32; off; off >>= 1) {
        a0 += __shfl_down(a0, off, 64);
        a1 += __shfl_down(a1, off, 64);
        a2 += __shfl_down(a2, off, 64);
        a3 += __shfl_down(a3, off, 64);
    }
    if (lane == 0) {
        float4 v; v.x = a0; v.y = a1; v.z = a2; v.w = a3;
        reinterpret_cast<float4*>(r)[wid] = v;
    }
}

__global__ void k_scan(float* __restrict__ r) {
    int b = blockIdx.x >> 2, e = blockIdx.x & 3;
    int lane = threadIdx.x;
    float carry = 0.f;
    for (int c = 0; c < S_ / 64; ++c) {
        int s = c * 64 + lane;
        float* p = r + ((size_t)(b * S_ + s)) * E_ + e;
        float v = *p;
        #pragma unroll
        for (int off = 1; off < 64; off <<= 1) {
            float u = __shfl_up(v, off, 64);
            if (lane >= off) v += u;
        }
        v += carry;
        *p = v;
        carry = __shfl(v, 63, 64);
    }
}

__global__ void k_route(const float* __restrict__ r, float* __restrict__ gate,
                        int* __restrict__ list, int* __restrict__ counts) {
    int t = blockIdx.x * blockDim.x + threadIdx.x;
    if (t >= T_) return;
    int s = t & (S_ - 1);
    float4 l4 = reinterpret_cast<const float4*>(r)[t];
    float inv = 1.f / (float)(s + 1);
    float l[4] = { l4.x * inv, l4.y * inv, l4.z * inv, l4.w * inv };
    int best = 0; float m = l[0];
    #pragma unroll
    for (int e = 1; e < 4; ++e) if (l[e] > m) { m = l[e]; best = e; }
    float sum = 0.f;
    #pragma unroll
    for (int e = 0; e < 4; ++e) sum += expf(l[e] - m);
    gate[t] = 1.f / sum;
    int pos = atomicAdd(&counts[best], 1);
    list[best * T_ + pos] = t;
}

__global__ void k_offs(const int* __restrict__ counts, int* __restrict__ offs,
                       int* __restrict__ pbase) {
    if (threadIdx.x == 0) {
        int a = 0, p = 0;
        pbase[0] = 0;
        for (int e = 0; e < E_; ++e) {
            offs[e] = a; a += counts[e];
            p += (counts[e] + 127) & ~127;
            pbase[e + 1] = p;
        }
    }
}

// ---------------- gather x into padded expert order, frag-tiled hi/lo ----------------
// Layout per plane: [g16][kb=D/32][lane64=kg*16+r15][8], elem k = kb*32+kg*8+j of row g*16+r15.
__global__ __launch_bounds__(256)
void k_gather(const float* __restrict__ x, const int* __restrict__ list,
              const int* __restrict__ counts, const int* __restrict__ pbase,
              ushort_t* __restrict__ Xh, ushort_t* __restrict__ Xl)
{
    constexpr int KB = D_ / 32;
    const int g = blockIdx.x;
    const int r15 = threadIdx.x & 15;
    const int kq = threadIdx.x >> 4;     // 0..15, 64 k's each
    const int v = g * 16 + r15;
    int e = 0;
    #pragma unroll
    for (int i = 0; i < E_; ++i) if (v >= pbase[i + 1]) e = i + 1;
    int token = -1;
    if (e < E_) {
        int local = v - pbase[e];
        if (local < counts[e]) token = list[e * T_ + local];
    }
    const float* xr = x + (size_t)(token >= 0 ? token : 0) * D_;
    #pragma unroll
    for (int c8 = 0; c8 < 8; ++c8) {
        const int k = kq * 64 + c8 * 8;
        float vv[8];
        if (token >= 0) {
            float4 u0 = *reinterpret_cast<const float4*>(xr + k);
            float4 u1 = *reinterpret_cast<const float4*>(xr + k + 4);
            vv[0]=u0.x; vv[1]=u0.y; vv[2]=u0.z; vv[3]=u0.w;
            vv[4]=u1.x; vv[5]=u1.y; vv[6]=u1.z; vv[7]=u1.w;
        } else {
            #pragma unroll
            for (int j = 0; j < 8; ++j) vv[j] = 0.f;
        }
        unsigned hw[4], lw[4];
        #pragma unroll
        for (int j = 0; j < 4; ++j) {
            ushort_t h0, l0, h1, l1;
            split_bf16(vv[2*j], h0, l0);
            split_bf16(vv[2*j+1], h1, l1);
            hw[j] = (unsigned)h0 | ((unsigned)h1 << 16);
            lw[j] = (unsigned)l0 | ((unsigned)l1 << 16);
        }
        size_t off = (((size_t)g * KB + (k >> 5)) * 64 + ((k >> 3) & 3) * 16 + r15) * 8;
        *reinterpret_cast<uint4*>(Xh + off) = make_uint4(hw[0], hw[1], hw[2], hw[3]);
        *reinterpret_cast<uint4*>(Xl + off) = make_uint4(lw[0], lw[1], lw[2], lw[3]);
    }
}

// ---------------- weight conversion to frag-order planes ----------------
// [e][nt=N/16][kb=K/32][64][8]; grid (N/128, K/32, E), 256 thr.
__global__ __launch_bounds__(256)
void k_convert_w(const float* __restrict__ W, ushort_t* __restrict__ Ph,
                 ushort_t* __restrict__ Pl, int K, int N) {
    const int e = blockIdx.z;
    const int n0 = blockIdx.x * 128;
    const int k0 = blockIdx.y * 32;
    const int kb = blockIdx.y;
    const int NT = N >> 4, KB = K >> 5;
    __shared__ float lf[32 * 128];
    const float* We = W + (size_t)e * K * N;
    const int tid = threadIdx.x;
    #pragma unroll
    for (int i = 0; i < 4; ++i) {
        int q = i * 256 + tid;
        int k = q >> 5, c4 = q & 31;
        float4 v = *reinterpret_cast<const float4*>(We + (size_t)(k0 + k) * N + n0 + c4 * 4);
        *reinterpret_cast<float4*>(lf + k * 128 + c4 * 4) = v;
    }
    __syncthreads();
    #pragma unroll
    for (int p = 0; p < 2; ++p) {
        int q = p * 256 + tid;
        int n = q & 127, kg = q >> 7;
        unsigned hw[4], lw[4];
        #pragma unroll
        for (int j = 0; j < 8; j += 2) {
            float f0 = lf[(kg * 8 + j) * 128 + n];
            float f1 = lf[(kg * 8 + j + 1) * 128 + n];
            ushort_t h0, l0, h1, l1;
            split_bf16(f0, h0, l0);
            split_bf16(f1, h1, l1);
            hw[j >> 1] = (unsigned)h0 | ((unsigned)h1 << 16);
            lw[j >> 1] = (unsigned)l0 | ((unsigned)l1 << 16);
        }
        size_t off = ((((size_t)e * NT + ((n0 + n) >> 4)) * KB + kb) * 64
                      + (kg * 16 + (n & 15))) * 8;
        *reinterpret_cast<uint4*>(Ph + off) = make_uint4(hw[0], hw[1], hw[2], hw[3]);
        *reinterpret_cast<uint4*>(Pl + off) = make_uint4(lw[0], lw[1], lw[2], lw[3]);
    }
}

// ---------------- main grouped GEMMs: ALL staging contiguous gload16 ----------------
// MODE 0: h(frag-order planes) = gelu(Xg @ w1 + b1)   K=1024, N=4096
// MODE 1: out(scatter,f32)     = gate*(h @ w2 + b2)   K=4096, N=1024
// Tile 128x128, BK=32, 4 waves (2x2), 64x64 per wave, split-bf16 3-pass MFMA.
template<int MODE>
__global__ __launch_bounds__(256)
void k_g3(const ushort_t* __restrict__ Ah, const ushort_t* __restrict__ Al,
          const ushort_t* __restrict__ Bh, const ushort_t* __restrict__ Bl,
          const float* __restrict__ bias, float* __restrict__ outF,
          ushort_t* __restrict__ outHh, ushort_t* __restrict__ outHl,
          const int* __restrict__ list, const int* __restrict__ counts,
          const int* __restrict__ pbase, const float* __restrict__ gate)
{
    constexpr int K  = (MODE == 0) ? D_ : F_;
    constexpr int N  = (MODE == 0) ? F_ : D_;
    constexpr int KB = K / 32;
    constexpr int NT = N / 16;
    constexpr int KBH = F_ / 32;

    const int e = blockIdx.z;
    const int cnt = counts[e];
    const int m0 = blockIdx.x * 128;
    if (m0 >= cnt) return;
    const int n0 = blockIdx.y * 128;
    const int pb = pbase[e];
    const int tid = threadIdx.x, wid = tid >> 6, lane = tid & 63;
    const int l15 = lane & 15, lkg = lane >> 4;
    const int wr = wid >> 1, wc = wid & 1;
    const int G0 = (pb + m0) >> 4;

    __shared__ __align__(16) ushort_t lds[16384];

    const ushort_t* aph[2]; const ushort_t* apl[2];
    const ushort_t* bph[2]; const ushort_t* bpl[2];
    #pragma unroll
    for (int i = 0; i < 2; ++i) {
        const int c = wid * 2 + i;
        size_t ab = ((size_t)(G0 + c) * KB) * 512 + (size_t)lane * 8;
        size_t bb = (((size_t)e * NT + (n0 >> 4) + c) * KB) * 512 + (size_t)lane * 8;
        aph[i] = Ah + ab; apl[i] = Al + ab;
        bph[i] = Bh + bb; bpl[i] = Bl + bb;
    }

    f32x4 acc[4][4];
    #pragma unroll
    for (int i = 0; i < 4; ++i)
        #pragma unroll
        for (int j = 0; j < 4; ++j) acc[i][j] = (f32x4){0.f, 0.f, 0.f, 0.f};

    for (int kb = 0; kb < KB; ++kb) {
        __syncthreads();
        const size_t kk = (size_t)kb * 512;
        #pragma unroll
        for (int i = 0; i < 2; ++i) {
            const int c = wid * 2 + i;
            gload16(aph[i] + kk, &lds[c * 512]);
            gload16(apl[i] + kk, &lds[4096 + c * 512]);
            gload16(bph[i] + kk, &lds[8192 + c * 512]);
            gload16(bpl[i] + kk, &lds[12288 + c * 512]);
        }
        __syncthreads();
        short8 ah[4], al[4], bh[4], bl[4];
        #pragma unroll
        for (int mi = 0; mi < 4; ++mi) {
            int rf = wr * 4 + mi;
            ah[mi] = *reinterpret_cast<const short8*>(&lds[rf * 512 + lane * 8]);
            al[mi] = *reinterpret_cast<const short8*>(&lds[4096 + rf * 512 + lane * 8]);
        }
        #pragma unroll
        for (int ni = 0; ni < 4; ++ni) {
            int nt = wc * 4 + ni;
            bh[ni] = *reinterpret_cast<const short8*>(&lds[8192 + nt * 512 + lane * 8]);
            bl[ni] = *reinterpret_cast<const short8*>(&lds[12288 + nt * 512 + lane * 8]);
        }
        #pragma unroll
        for (int mi = 0; mi < 4; ++mi)
            #pragma unroll
            for (int ni = 0; ni < 4; ++ni) {
                acc[mi][ni] = __builtin_amdgcn_mfma_f32_16x16x32_bf16(ah[mi], bh[ni], acc[mi][ni], 0, 0, 0);
                acc[mi][ni] = __builtin_amdgcn_mfma_f32_16x16x32_bf16(ah[mi], bl[ni], acc[mi][ni], 0, 0, 0);
                acc[mi][ni] = __builtin_amdgcn_mfma_f32_16x16x32_bf16(al[mi], bh[ni], acc[mi][ni], 0, 0, 0);
            }
    }

    const float* be = bias + (size_t)e * N;
    if (MODE == 0) {
        // write h in frag-order planes (padded rows included; they never reach out)
        #pragma unroll
        for (int mi = 0; mi < 4; ++mi) {
            const int g2 = G0 + wr * 4 + mi;
            #pragma unroll
            for (int rg = 0; rg < 4; ++rg) {
                const int r15o = lkg * 4 + rg;
                #pragma unroll
                for (int ni = 0; ni < 4; ++ni) {
                    const int f = n0 + wc * 64 + ni * 16 + l15;
                    float v = acc[mi][ni][rg] + be[f];
                    float u = 1.5957691216057308f * (v + 0.044715f * v * v * v);
                    v = v / (1.f + __expf(-u));
                    ushort_t h, l;
                    split_bf16(v, h, l);
                    size_t off = (((size_t)g2 * KBH + (f >> 5)) * 64
                                  + ((f >> 3) & 3) * 16 + r15o) * 8 + (f & 7);
                    outHh[off] = h;
                    outHl[off] = l;
                }
            }
        }
    } else {
        const int* lst = list + (size_t)e * T_;
        #pragma unroll
        for (int mi = 0; mi < 4; ++mi) {
            #pragma unroll
            for (int rg = 0; rg < 4; ++rg) {
                int rm = m0 + wr * 64 + mi * 16 + lkg * 4 + rg;
                if (rm >= cnt) continue;
                int t = lst[rm];
                float gv = gate[t];
                float* crow = outF + (size_t)t * (size_t)N;
                #pragma unroll
                for (int ni = 0; ni < 4; ++ni) {
                    int col = n0 + wc * 64 + ni * 16 + l15;
                    crow[col] = gv * (acc[mi][ni][rg] + be[col]);
                }
            }
        }
    }
}

// ---------------- tier-B fallback (round-2 proven path) ----------------

__global__ void k_convert_x(const float* __restrict__ x,
                            ushort_t* __restrict__ xh, ushort_t* __restrict__ xl) {
    size_t i = ((size_t)blockIdx.x * 256 + threadIdx.x) * 8;
    float4 a = *reinterpret_cast<const float4*>(x + i);
    float4 b = *reinterpret_cast<const float4*>(x + i + 4);
    float v[8] = { a.x, a.y, a.z, a.w, b.x, b.y, b.z, b.w };
    unsigned hw[4], lw[4];
    #pragma unroll
    for (int j = 0; j < 4; ++j) {
        ushort_t h0, l0, h1, l1;
        split_bf16(v[2*j], h0, l0);
        split_bf16(v[2*j+1], h1, l1);
        hw[j] = (unsigned)h0 | ((unsigned)h1 << 16);
        lw[j] = (unsigned)l0 | ((unsigned)l1 << 16);
    }
    *reinterpret_cast<uint4*>(xh + i) = make_uint4(hw[0], hw[1], hw[2], hw[3]);
    *reinterpret_cast<uint4*>(xl + i) = make_uint4(lw[0], lw[1], lw[2], lw[3]);
}

template<int MODE>
__global__ __launch_bounds__(256)
void k_gemm2(const ushort_t* __restrict__ Ah, const ushort_t* __restrict__ Al,
             const ushort_t* __restrict__ Bh, const ushort_t* __restrict__ Bl,
             const float* __restrict__ bias, float* __restrict__ outF,
             ushort_t* __restrict__ outHh, ushort_t* __restrict__ outHl,
             const int* __restrict__ list, const int* __restrict__ counts,
             const int* __restrict__ offs, const float* __restrict__ gate,
             int K, int N, int NT)
{
    const int e = blockIdx.z;
    const int cnt = counts[e];
    const int m0 = blockIdx.x * 128;
    if (m0 >= cnt) return;
    const int n0 = blockIdx.y * 128;
    const int hbase = offs[e];
    const int KB = K >> 5;
    const int tid = threadIdx.x, wid = tid >> 6, lane = tid & 63;
    const int l15 = lane & 15, lkg = lane >> 4;
    const int* lst = list + (size_t)e * T_;
    __shared__ __align__(16) ushort_t lds[16384];
    size_t a_rel[2], b_rel[2];
    #pragma unroll
    for (int i = 0; i < 2; ++i) {
        int rf = wid * 2 + i;
        int rm = m0 + rf * 16 + l15;
        int rr = rm < cnt ? rm : cnt - 1;
        size_t row = (MODE == 0) ? (size_t)lst[rr] : (size_t)(hbase + rr);
        a_rel[i] = row * (size_t)K + (size_t)lkg * 8;
        b_rel[i] = (((size_t)e * NT + (n0 >> 4) + rf) * (size_t)KB) * 512 + (size_t)lane * 8;
    }
    const int wr = wid >> 1, wc = wid & 1;
    f32x4 acc[4][4];
    #pragma unroll
    for (int i = 0; i < 4; ++i)
        #pragma unroll
        for (int j = 0; j < 4; ++j) acc[i][j] = (f32x4){0.f, 0.f, 0.f, 0.f};
    for (int kb = 0; kb < KB; ++kb) {
        __syncthreads();
        #pragma unroll
        for (int i = 0; i < 2; ++i) {
            int c = wid * 2 + i;
            gload16(Ah + a_rel[i] + (size_t)kb * 32, &lds[c * 512]);
            gload16(Al + a_rel[i] + (size_t)kb * 32, &lds[4096 + c * 512]);
            gload16(Bh + b_rel[i] + (size_t)kb * 512, &lds[8192 + c * 512]);
            gload16(Bl + b_rel[i] + (size_t)kb * 512, &lds[12288 + c * 512]);
        }
        __syncthreads();
        short8 ah[4], al[4], bh[4], bl[4];
        #pragma unroll
        for (int mi = 0; mi < 4; ++mi) {
            int rf = wr * 4 + mi;
            ah[mi] = *reinterpret_cast<const short8*>(&lds[rf * 512 + lane * 8]);
            al[mi] = *reinterpret_cast<const short8*>(&lds[4096 + rf * 512 + lane * 8]);
        }
        #pragma unroll
        for (int ni = 0; ni < 4; ++ni) {
            int nt = wc * 4 + ni;
            bh[ni] = *reinterpret_cast<const short8*>(&lds[8192 + nt * 512 + lane * 8]);
            bl[ni] = *reinterpret_cast<const short8*>(&lds[12288 + nt * 512 + lane * 8]);
        }
        #pragma unroll
        for (int mi = 0; mi < 4; ++mi)
            #pragma unroll
            for (int ni = 0; ni < 4; ++ni) {
                acc[mi][ni] = __builtin_amdgcn_mfma_f32_16x16x32_bf16(ah[mi], bh[ni], acc[mi][ni], 0, 0, 0);
                acc[mi][ni] = __builtin_amdgcn_mfma_f32_16x16x32_bf16(ah[mi], bl[ni], acc[mi][ni], 0, 0, 0);
                acc[mi][ni] = __builtin_amdgcn_mfma_f32_16x16x32_bf16(al[mi], bh[ni], acc[mi][ni], 0, 0, 0);
            }
    }
    const float* be = bias + (size_t)e * N;
    #pragma unroll
    for (int mi = 0; mi < 4; ++mi) {
        #pragma unroll
        for (int rg = 0; rg < 4; ++rg) {
            int rm = m0 + wr * 64 + mi * 16 + lkg * 4 + rg;
            if (rm >= cnt) continue;
            if (MODE == 0) {
                size_t rowb = (size_t)(hbase + rm) * (size_t)F_;
                #pragma unroll
                for (int ni = 0; ni < 4; ++ni) {
                    int col = n0 + wc * 64 + ni * 16 + l15;
                    float v = acc[mi][ni][rg] + be[col];
                    float u = 1.5957691216057308f * (v + 0.044715f * v * v * v);
                    v = v / (1.f + __expf(-u));
                    ushort_t h, l;
                    split_bf16(v, h, l);
                    outHh[rowb + col] = h;
                    outHl[rowb + col] = l;
                }
            } else {
                int t = lst[rm];
                float gv = gate[t];
                float* crow = outF + (size_t)t * (size_t)N;
                #pragma unroll
                for (int ni = 0; ni < 4; ++ni) {
                    int col = n0 + wc * 64 + ni * 16 + l15;
                    crow[col] = gv * (acc[mi][ni][rg] + be[col]);
                }
            }
        }
    }
}

// ---------------- launch ----------------

extern "C" void kernel_launch(void* const* d_in, const int* in_sizes, int n_in,
                              void* d_out, int out_size, void* d_ws, size_t ws_size,
                              hipStream_t stream) {
    const float* x   = (const float*)d_in[0];
    const float* rw  = (const float*)d_in[1];
    const float* w1  = (const float*)d_in[2];
    const float* b1  = (const float*)d_in[3];
    const float* w2  = (const float*)d_in[4];
    const float* b2  = (const float*)d_in[5];
    float* out = (float*)d_out;

    const size_t HCAP = (size_t)PCAP_ * F_;     // 35.65M u16 per plane
    const size_t XCAP = (size_t)PCAP_ * D_;     // 8.91M
    const size_t WCAP = (size_t)E_ * D_ * F_;   // 16.78M
    const size_t misc = ((size_t)T_ * E_ + T_ + (size_t)E_ * T_) * 4 + 256;

    const size_t need_A = (2 * HCAP + 2 * XCAP + 2 * WCAP) * 2 + misc;   // ~246 MB
    const size_t hf = (size_t)T_ * F_;
    const size_t xd = (size_t)T_ * D_;
    const size_t need_B = (2 * hf + 2 * xd + 2 * WCAP) * 2 + misc;       // ~201 MB

    if (ws_size >= need_A) {
        ushort_t* hh  = (ushort_t*)d_ws;
        ushort_t* hl  = hh + HCAP;
        ushort_t* xh  = hl + HCAP;
        ushort_t* xl  = xh + XCAP;
        ushort_t* wph = xl + XCAP;
        ushort_t* wpl = wph + WCAP;
        float* r    = (float*)(wpl + WCAP);
        float* gate = r + (size_t)T_ * E_;
        int* list   = (int*)(gate + T_);
        int* counts = list + (size_t)E_ * T_;
        int* offs   = counts + E_;
        int* pbase  = offs + E_;

        k_router<<<T_ / 4, 256, 0, stream>>>(x, rw, r, counts);
        k_convert_w<<<dim3(F_ / 128, D_ / 32, E_), 256, 0, stream>>>(w1, wph, wpl, D_, F_);
        k_scan<<<B_ * E_, 64, 0, stream>>>(r);
        k_route<<<T_ / 256, 256, 0, stream>>>(r, gate, list, counts);
        k_offs<<<1, 64, 0, stream>>>(counts, offs, pbase);
        k_gather<<<GCAP_, 256, 0, stream>>>(x, list, counts, pbase, xh, xl);

        k_g3<0><<<dim3(T_ / 128, F_ / 128, E_), 256, 0, stream>>>(
            xh, xl, wph, wpl, b1, nullptr, hh, hl, list, counts, pbase, nullptr);
        k_convert_w<<<dim3(D_ / 128, F_ / 32, E_), 256, 0, stream>>>(w2, wph, wpl, F_, D_);
        k_g3<1><<<dim3(T_ / 128, D_ / 128, E_), 256, 0, stream>>>(
            hh, hl, wph, wpl, b2, out, nullptr, nullptr, list, counts, pbase, gate);
    } else if (ws_size >= need_B) {
        ushort_t* hh  = (ushort_t*)d_ws;
        ushort_t* hl  = hh + hf;
        ushort_t* xh  = hl + hf;
        ushort_t* xl  = xh + xd;
        ushort_t* wph = xl + xd;
        ushort_t* wpl = wph + WCAP;
        float* r    = (float*)(wpl + WCAP);
        float* gate = r + (size_t)T_ * E_;
        int* list   = (int*)(gate + T_);
        int* counts = list + (size_t)E_ * T_;
        int* offs   = counts + E_;
        int* pbase  = offs + E_;

        k_router<<<T_ / 4, 256, 0, stream>>>(x, rw, r, counts);
        k_convert_x<<<(int)(xd / 2048), 256, 0, stream>>>(x, xh, xl);
        k_convert_w<<<dim3(F_ / 128, D_ / 32, E_), 256, 0, stream>>>(w1, wph, wpl, D_, F_);
        k_scan<<<B_ * E_, 64, 0, stream>>>(r);
        k_route<<<T_ / 256, 256, 0, stream>>>(r, gate, list, counts);
        k_offs<<<1, 64, 0, stream>>>(counts, offs, pbase);

        k_gemm2<0><<<dim3(T_ / 128, F_ / 128, E_), 256, 0, stream>>>(
            xh, xl, wph, wpl, b1, nullptr, hh, hl, list, counts, offs, nullptr,
            D_, F_, F_ / 16);
        k_convert_w<<<dim3(D_ / 128, F_ / 32, E_), 256, 0, stream>>>(w2, wph, wpl, F_, D_);
        k_gemm2<1><<<dim3(T_ / 128, D_ / 128, E_), 256, 0, stream>>>(
            hh, hl, wph, wpl, b2, out, nullptr, nullptr, list, counts, offs, gate,
            F_, D_, D_ / 16);
    }
    // else: ws too small -> leave poison, fail loudly
}

// Round 4
// 970.510 us; speedup vs baseline: 1.1876x; 1.1393x over previous
//
#include <hip/hip_runtime.h>
#include <math.h>

#define B_ 4
#define S_ 2048
#define D_ 1024
#define F_ 4096
#define E_ 4
#define T_ (B_*S_)        // 8192 tokens
#define PCAP_ 8704        // max padded rows: 8192 + 4*127 rounded to 128
#define GCAP_ (PCAP_/16)  // 544 row-groups

typedef unsigned short ushort_t;
typedef __attribute__((ext_vector_type(8))) short short8;
typedef __attribute__((ext_vector_type(4))) float f32x4;

__device__ __forceinline__ ushort_t f2bf_rne(float f) {
    unsigned u = __float_as_uint(f);
    unsigned r = 0x7FFFu + ((u >> 16) & 1u);
    u += r;
    return (ushort_t)(u >> 16);
}
__device__ __forceinline__ float bf2f(ushort_t h) {
    return __uint_as_float(((unsigned)h) << 16);
}
__device__ __forceinline__ void split_bf16(float f, ushort_t &hi, ushort_t &lo) {
    hi = f2bf_rne(f);
    lo = f2bf_rne(f - bf2f(hi));
}

__device__ __forceinline__ void gload16(const void* g, void* l) {
    __builtin_amdgcn_global_load_lds(
        (const __attribute__((address_space(1))) unsigned int*)g,
        (__attribute__((address_space(3))) unsigned int*)l, 16, 0, 0);
}

// ---------------- routing ----------------

__global__ void k_router(const float* __restrict__ x, const float* __restrict__ rw,
                         float* __restrict__ r, int* __restrict__ counts) {
    if (blockIdx.x == 0 && threadIdx.x < E_) counts[threadIdx.x] = 0;
    int wid = blockIdx.x * 4 + (threadIdx.x >> 6);
    int lane = threadIdx.x & 63;
    const float* xr = x + (size_t)wid * D_;
    float a0 = 0.f, a1 = 0.f, a2 = 0.f, a3 = 0.f;
    for (int i = lane; i < D_; i += 64) {
        float xv = xr[i];
        float4 w = reinterpret_cast<const float4*>(rw)[i];
        a0 += xv * w.x; a1 += xv * w.y; a2 += xv * w.z; a3 += xv * w.w;
    }
    for (int off = 32; off; off >>= 1) {
        a0 += __shfl_down(a0, off, 64);
        a1 += __shfl_down(a1, off, 64);
        a2 += __shfl_down(a2, off, 64);
        a3 += __shfl_down(a3, off, 64);
    }
    if (lane == 0) {
        float4 v; v.x = a0; v.y = a1; v.z = a2; v.w = a3;
        reinterpret_cast<float4*>(r)[wid] = v;
    }
}

__global__ void k_scan(float* __restrict__ r) {
    int b = blockIdx.x >> 2, e = blockIdx.x & 3;
    int lane = threadIdx.x;
    float carry = 0.f;
    for (int c = 0; c < S_ / 64; ++c) {
        int s = c * 64 + lane;
        float* p = r + ((size_t)(b * S_ + s)) * E_ + e;
        float v = *p;
        #pragma unroll
        for (int off = 1; off < 64; off <<= 1) {
            float u = __shfl_up(v, off, 64);
            if (lane >= off) v += u;
        }
        v += carry;
        *p = v;
        carry = __shfl(v, 63, 64);
    }
}

__global__ void k_route(const float* __restrict__ r, float* __restrict__ gate,
                        int* __restrict__ list, int* __restrict__ counts) {
    int t = blockIdx.x * blockDim.x + threadIdx.x;
    if (t >= T_) return;
    int s = t & (S_ - 1);
    float4 l4 = reinterpret_cast<const float4*>(r)[t];
    float inv = 1.f / (float)(s + 1);
    float l[4] = { l4.x * inv, l4.y * inv, l4.z * inv, l4.w * inv };
    int best = 0; float m = l[0];
    #pragma unroll
    for (int e = 1; e < 4; ++e) if (l[e] > m) { m = l[e]; best = e; }
    float sum = 0.f;
    #pragma unroll
    for (int e = 0; e < 4; ++e) sum += expf(l[e] - m);
    gate[t] = 1.f / sum;
    int pos = atomicAdd(&counts[best], 1);
    list[best * T_ + pos] = t;
}

__global__ void k_offs(const int* __restrict__ counts, int* __restrict__ offs,
                       int* __restrict__ pbase) {
    if (threadIdx.x == 0) {
        int a = 0, p = 0;
        pbase[0] = 0;
        for (int e = 0; e < E_; ++e) {
            offs[e] = a; a += counts[e];
            p += (counts[e] + 127) & ~127;
            pbase[e + 1] = p;
        }
    }
}

// ---------------- gather x into padded expert order, frag-tiled hi/lo ----------------
__global__ __launch_bounds__(256)
void k_gather(const float* __restrict__ x, const int* __restrict__ list,
              const int* __restrict__ counts, const int* __restrict__ pbase,
              ushort_t* __restrict__ Xh, ushort_t* __restrict__ Xl)
{
    constexpr int KB = D_ / 32;
    const int g = blockIdx.x;
    const int r15 = threadIdx.x & 15;
    const int kq = threadIdx.x >> 4;
    const int v = g * 16 + r15;
    int e = 0;
    #pragma unroll
    for (int i = 0; i < E_; ++i) if (v >= pbase[i + 1]) e = i + 1;
    int token = -1;
    if (e < E_) {
        int local = v - pbase[e];
        if (local < counts[e]) token = list[e * T_ + local];
    }
    const float* xr = x + (size_t)(token >= 0 ? token : 0) * D_;
    #pragma unroll
    for (int c8 = 0; c8 < 8; ++c8) {
        const int k = kq * 64 + c8 * 8;
        float vv[8];
        if (token >= 0) {
            float4 u0 = *reinterpret_cast<const float4*>(xr + k);
            float4 u1 = *reinterpret_cast<const float4*>(xr + k + 4);
            vv[0]=u0.x; vv[1]=u0.y; vv[2]=u0.z; vv[3]=u0.w;
            vv[4]=u1.x; vv[5]=u1.y; vv[6]=u1.z; vv[7]=u1.w;
        } else {
            #pragma unroll
            for (int j = 0; j < 8; ++j) vv[j] = 0.f;
        }
        unsigned hw[4], lw[4];
        #pragma unroll
        for (int j = 0; j < 4; ++j) {
            ushort_t h0, l0, h1, l1;
            split_bf16(vv[2*j], h0, l0);
            split_bf16(vv[2*j+1], h1, l1);
            hw[j] = (unsigned)h0 | ((unsigned)h1 << 16);
            lw[j] = (unsigned)l0 | ((unsigned)l1 << 16);
        }
        size_t off = (((size_t)g * KB + (k >> 5)) * 64 + ((k >> 3) & 3) * 16 + r15) * 8;
        *reinterpret_cast<uint4*>(Xh + off) = make_uint4(hw[0], hw[1], hw[2], hw[3]);
        *reinterpret_cast<uint4*>(Xl + off) = make_uint4(lw[0], lw[1], lw[2], lw[3]);
    }
}

// ---------------- weight conversion to frag-order planes ----------------
__global__ __launch_bounds__(256)
void k_convert_w(const float* __restrict__ W, ushort_t* __restrict__ Ph,
                 ushort_t* __restrict__ Pl, int K, int N) {
    const int e = blockIdx.z;
    const int n0 = blockIdx.x * 128;
    const int k0 = blockIdx.y * 32;
    const int kb = blockIdx.y;
    const int NT = N >> 4, KB = K >> 5;
    __shared__ float lf[32 * 128];
    const float* We = W + (size_t)e * K * N;
    const int tid = threadIdx.x;
    #pragma unroll
    for (int i = 0; i < 4; ++i) {
        int q = i * 256 + tid;
        int k = q >> 5, c4 = q & 31;
        float4 v = *reinterpret_cast<const float4*>(We + (size_t)(k0 + k) * N + n0 + c4 * 4);
        *reinterpret_cast<float4*>(lf + k * 128 + c4 * 4) = v;
    }
    __syncthreads();
    #pragma unroll
    for (int p = 0; p < 2; ++p) {
        int q = p * 256 + tid;
        int n = q & 127, kg = q >> 7;
        unsigned hw[4], lw[4];
        #pragma unroll
        for (int j = 0; j < 8; j += 2) {
            float f0 = lf[(kg * 8 + j) * 128 + n];
            float f1 = lf[(kg * 8 + j + 1) * 128 + n];
            ushort_t h0, l0, h1, l1;
            split_bf16(f0, h0, l0);
            split_bf16(f1, h1, l1);
            hw[j >> 1] = (unsigned)h0 | ((unsigned)h1 << 16);
            lw[j >> 1] = (unsigned)l0 | ((unsigned)l1 << 16);
        }
        size_t off = ((((size_t)e * NT + ((n0 + n) >> 4)) * KB + kb) * 64
                      + (kg * 16 + (n & 15))) * 8;
        *reinterpret_cast<uint4*>(Ph + off) = make_uint4(hw[0], hw[1], hw[2], hw[3]);
        *reinterpret_cast<uint4*>(Pl + off) = make_uint4(lw[0], lw[1], lw[2], lw[3]);
    }
}

// ---------------- main grouped GEMMs: 2-phase double-buffered pipeline ----------------
// MODE 0: h(frag-order planes) = gelu(Xg @ w1 + b1)   K=1024, N=4096
// MODE 1: out(scatter,f32)     = gate*(h @ w2 + b2)   K=4096, N=1024
// Tile 128x128, BK=32, 4 waves (2x2), 64x64 per wave, split-bf16 3-pass MFMA.
// Pipeline: STAGE(buf^1, t+1) issued BEFORE compute(buf,t); one __syncthreads()
// per k-step at the end (implicit vmcnt(0) drains prefetch after MFMA cover).
template<int MODE>
__global__ __launch_bounds__(256)
void k_g4(const ushort_t* __restrict__ Ah, const ushort_t* __restrict__ Al,
          const ushort_t* __restrict__ Bh, const ushort_t* __restrict__ Bl,
          const float* __restrict__ bias, float* __restrict__ outF,
          ushort_t* __restrict__ outHh, ushort_t* __restrict__ outHl,
          const int* __restrict__ list, const int* __restrict__ counts,
          const int* __restrict__ pbase, const float* __restrict__ gate)
{
    constexpr int K  = (MODE == 0) ? D_ : F_;
    constexpr int N  = (MODE == 0) ? F_ : D_;
    constexpr int KB = K / 32;
    constexpr int NT = N / 16;
    constexpr int KBH = F_ / 32;

    const int e = blockIdx.z;
    const int cnt = counts[e];
    const int m0 = blockIdx.x * 128;
    if (m0 >= cnt) return;
    const int n0 = blockIdx.y * 128;
    const int pb = pbase[e];
    const int tid = threadIdx.x, wid = tid >> 6, lane = tid & 63;
    const int l15 = lane & 15, lkg = lane >> 4;
    const int wr = wid >> 1, wc = wid & 1;
    const int G0 = (pb + m0) >> 4;

    // double-buffered: each buffer = Ah[8][512] @0, Al @4096, Bh @8192, Bl @12288
    __shared__ __align__(16) ushort_t lds[2][16384];

    const ushort_t* aph[2]; const ushort_t* apl[2];
    const ushort_t* bph[2]; const ushort_t* bpl[2];
    #pragma unroll
    for (int i = 0; i < 2; ++i) {
        const int c = wid * 2 + i;
        size_t ab = ((size_t)(G0 + c) * KB) * 512 + (size_t)lane * 8;
        size_t bb = (((size_t)e * NT + (n0 >> 4) + c) * KB) * 512 + (size_t)lane * 8;
        aph[i] = Ah + ab; apl[i] = Al + ab;
        bph[i] = Bh + bb; bpl[i] = Bl + bb;
    }

    f32x4 acc[4][4];
    #pragma unroll
    for (int i = 0; i < 4; ++i)
        #pragma unroll
        for (int j = 0; j < 4; ++j) acc[i][j] = (f32x4){0.f, 0.f, 0.f, 0.f};

    // ---- prologue: stage tile 0 into buf 0 ----
    {
        ushort_t* L = &lds[0][0];
        #pragma unroll
        for (int i = 0; i < 2; ++i) {
            const int c = wid * 2 + i;
            gload16(aph[i], L + c * 512);
            gload16(apl[i], L + 4096 + c * 512);
            gload16(bph[i], L + 8192 + c * 512);
            gload16(bpl[i], L + 12288 + c * 512);
        }
    }
    __syncthreads();   // drains vmcnt(0): buf0 ready

    int cur = 0;
    for (int kb = 0; kb < KB; ++kb) {
        // ---- issue prefetch of tile kb+1 into buf[cur^1] (before compute) ----
        if (kb + 1 < KB) {
            ushort_t* L = &lds[cur ^ 1][0];
            const size_t kk = (size_t)(kb + 1) * 512;
            #pragma unroll
            for (int i = 0; i < 2; ++i) {
                const int c = wid * 2 + i;
                gload16(aph[i] + kk, L + c * 512);
                gload16(apl[i] + kk, L + 4096 + c * 512);
                gload16(bph[i] + kk, L + 8192 + c * 512);
                gload16(bpl[i] + kk, L + 12288 + c * 512);
            }
        }
        // ---- compute on buf[cur] ----
        const ushort_t* L = &lds[cur][0];
        short8 ah[4], al[4], bh[4], bl[4];
        #pragma unroll
        for (int mi = 0; mi < 4; ++mi) {
            int rf = wr * 4 + mi;
            ah[mi] = *reinterpret_cast<const short8*>(&L[rf * 512 + lane * 8]);
            al[mi] = *reinterpret_cast<const short8*>(&L[4096 + rf * 512 + lane * 8]);
        }
        #pragma unroll
        for (int ni = 0; ni < 4; ++ni) {
            int nt = wc * 4 + ni;
            bh[ni] = *reinterpret_cast<const short8*>(&L[8192 + nt * 512 + lane * 8]);
            bl[ni] = *reinterpret_cast<const short8*>(&L[12288 + nt * 512 + lane * 8]);
        }
        __builtin_amdgcn_s_setprio(1);
        #pragma unroll
        for (int mi = 0; mi < 4; ++mi)
            #pragma unroll
            for (int ni = 0; ni < 4; ++ni) {
                acc[mi][ni] = __builtin_amdgcn_mfma_f32_16x16x32_bf16(ah[mi], bh[ni], acc[mi][ni], 0, 0, 0);
                acc[mi][ni] = __builtin_amdgcn_mfma_f32_16x16x32_bf16(ah[mi], bl[ni], acc[mi][ni], 0, 0, 0);
                acc[mi][ni] = __builtin_amdgcn_mfma_f32_16x16x32_bf16(al[mi], bh[ni], acc[mi][ni], 0, 0, 0);
            }
        __builtin_amdgcn_s_setprio(0);
        // end-of-step barrier: implicit vmcnt(0)+lgkmcnt(0) drains the prefetch
        // and protects buf[cur] before next iteration overwrites it.
        __syncthreads();
        cur ^= 1;
    }

    const float* be = bias + (size_t)e * N;
    if (MODE == 0) {
        #pragma unroll
        for (int mi = 0; mi < 4; ++mi) {
            const int g2 = G0 + wr * 4 + mi;
            #pragma unroll
            for (int rg = 0; rg < 4; ++rg) {
                const int r15o = lkg * 4 + rg;
                #pragma unroll
                for (int ni = 0; ni < 4; ++ni) {
                    const int f = n0 + wc * 64 + ni * 16 + l15;
                    float v = acc[mi][ni][rg] + be[f];
                    float u = 1.5957691216057308f * (v + 0.044715f * v * v * v);
                    v = v / (1.f + __expf(-u));
                    ushort_t h, l;
                    split_bf16(v, h, l);
                    size_t off = (((size_t)g2 * KBH + (f >> 5)) * 64
                                  + ((f >> 3) & 3) * 16 + r15o) * 8 + (f & 7);
                    outHh[off] = h;
                    outHl[off] = l;
                }
            }
        }
    } else {
        const int* lst = list + (size_t)e * T_;
        #pragma unroll
        for (int mi = 0; mi < 4; ++mi) {
            #pragma unroll
            for (int rg = 0; rg < 4; ++rg) {
                int rm = m0 + wr * 64 + mi * 16 + lkg * 4 + rg;
                if (rm >= cnt) continue;
                int t = lst[rm];
                float gv = gate[t];
                float* crow = outF + (size_t)t * (size_t)N;
                #pragma unroll
                for (int ni = 0; ni < 4; ++ni) {
                    int col = n0 + wc * 64 + ni * 16 + l15;
                    crow[col] = gv * (acc[mi][ni][rg] + be[col]);
                }
            }
        }
    }
}

// ---------------- tier-B fallback (round-2 proven path) ----------------

__global__ void k_convert_x(const float* __restrict__ x,
                            ushort_t* __restrict__ xh, ushort_t* __restrict__ xl) {
    size_t i = ((size_t)blockIdx.x * 256 + threadIdx.x) * 8;
    float4 a = *reinterpret_cast<const float4*>(x + i);
    float4 b = *reinterpret_cast<const float4*>(x + i + 4);
    float v[8] = { a.x, a.y, a.z, a.w, b.x, b.y, b.z, b.w };
    unsigned hw[4], lw[4];
    #pragma unroll
    for (int j = 0; j < 4; ++j) {
        ushort_t h0, l0, h1, l1;
        split_bf16(v[2*j], h0, l0);
        split_bf16(v[2*j+1], h1, l1);
        hw[j] = (unsigned)h0 | ((unsigned)h1 << 16);
        lw[j] = (unsigned)l0 | ((unsigned)l1 << 16);
    }
    *reinterpret_cast<uint4*>(xh + i) = make_uint4(hw[0], hw[1], hw[2], hw[3]);
    *reinterpret_cast<uint4*>(xl + i) = make_uint4(lw[0], lw[1], lw[2], lw[3]);
}

template<int MODE>
__global__ __launch_bounds__(256)
void k_gemm2(const ushort_t* __restrict__ Ah, const ushort_t* __restrict__ Al,
             const ushort_t* __restrict__ Bh, const ushort_t* __restrict__ Bl,
             const float* __restrict__ bias, float* __restrict__ outF,
             ushort_t* __restrict__ outHh, ushort_t* __restrict__ outHl,
             const int* __restrict__ list, const int* __restrict__ counts,
             const int* __restrict__ offs, const float* __restrict__ gate,
             int K, int N, int NT)
{
    const int e = blockIdx.z;
    const int cnt = counts[e];
    const int m0 = blockIdx.x * 128;
    if (m0 >= cnt) return;
    const int n0 = blockIdx.y * 128;
    const int hbase = offs[e];
    const int KB = K >> 5;
    const int tid = threadIdx.x, wid = tid >> 6, lane = tid & 63;
    const int l15 = lane & 15, lkg = lane >> 4;
    const int* lst = list + (size_t)e * T_;
    __shared__ __align__(16) ushort_t lds[16384];
    size_t a_rel[2], b_rel[2];
    #pragma unroll
    for (int i = 0; i < 2; ++i) {
        int rf = wid * 2 + i;
        int rm = m0 + rf * 16 + l15;
        int rr = rm < cnt ? rm : cnt - 1;
        size_t row = (MODE == 0) ? (size_t)lst[rr] : (size_t)(hbase + rr);
        a_rel[i] = row * (size_t)K + (size_t)lkg * 8;
        b_rel[i] = (((size_t)e * NT + (n0 >> 4) + rf) * (size_t)KB) * 512 + (size_t)lane * 8;
    }
    const int wr = wid >> 1, wc = wid & 1;
    f32x4 acc[4][4];
    #pragma unroll
    for (int i = 0; i < 4; ++i)
        #pragma unroll
        for (int j = 0; j < 4; ++j) acc[i][j] = (f32x4){0.f, 0.f, 0.f, 0.f};
    for (int kb = 0; kb < KB; ++kb) {
        __syncthreads();
        #pragma unroll
        for (int i = 0; i < 2; ++i) {
            int c = wid * 2 + i;
            gload16(Ah + a_rel[i] + (size_t)kb * 32, &lds[c * 512]);
            gload16(Al + a_rel[i] + (size_t)kb * 32, &lds[4096 + c * 512]);
            gload16(Bh + b_rel[i] + (size_t)kb * 512, &lds[8192 + c * 512]);
            gload16(Bl + b_rel[i] + (size_t)kb * 512, &lds[12288 + c * 512]);
        }
        __syncthreads();
        short8 ah[4], al[4], bh[4], bl[4];
        #pragma unroll
        for (int mi = 0; mi < 4; ++mi) {
            int rf = wr * 4 + mi;
            ah[mi] = *reinterpret_cast<const short8*>(&lds[rf * 512 + lane * 8]);
            al[mi] = *reinterpret_cast<const short8*>(&lds[4096 + rf * 512 + lane * 8]);
        }
        #pragma unroll
        for (int ni = 0; ni < 4; ++ni) {
            int nt = wc * 4 + ni;
            bh[ni] = *reinterpret_cast<const short8*>(&lds[8192 + nt * 512 + lane * 8]);
            bl[ni] = *reinterpret_cast<const short8*>(&lds[12288 + nt * 512 + lane * 8]);
        }
        #pragma unroll
        for (int mi = 0; mi < 4; ++mi)
            #pragma unroll
            for (int ni = 0; ni < 4; ++ni) {
                acc[mi][ni] = __builtin_amdgcn_mfma_f32_16x16x32_bf16(ah[mi], bh[ni], acc[mi][ni], 0, 0, 0);
                acc[mi][ni] = __builtin_amdgcn_mfma_f32_16x16x32_bf16(ah[mi], bl[ni], acc[mi][ni], 0, 0, 0);
                acc[mi][ni] = __builtin_amdgcn_mfma_f32_16x16x32_bf16(al[mi], bh[ni], acc[mi][ni], 0, 0, 0);
            }
    }
    const float* be = bias + (size_t)e * N;
    #pragma unroll
    for (int mi = 0; mi < 4; ++mi) {
        #pragma unroll
        for (int rg = 0; rg < 4; ++rg) {
            int rm = m0 + wr * 64 + mi * 16 + lkg * 4 + rg;
            if (rm >= cnt) continue;
            if (MODE == 0) {
                size_t rowb = (size_t)(hbase + rm) * (size_t)F_;
                #pragma unroll
                for (int ni = 0; ni < 4; ++ni) {
                    int col = n0 + wc * 64 + ni * 16 + l15;
                    float v = acc[mi][ni][rg] + be[col];
                    float u = 1.5957691216057308f * (v + 0.044715f * v * v * v);
                    v = v / (1.f + __expf(-u));
                    ushort_t h, l;
                    split_bf16(v, h, l);
                    outHh[rowb + col] = h;
                    outHl[rowb + col] = l;
                }
            } else {
                int t = lst[rm];
                float gv = gate[t];
                float* crow = outF + (size_t)t * (size_t)N;
                #pragma unroll
                for (int ni = 0; ni < 4; ++ni) {
                    int col = n0 + wc * 64 + ni * 16 + l15;
                    crow[col] = gv * (acc[mi][ni][rg] + be[col]);
                }
            }
        }
    }
}

// ---------------- launch ----------------

extern "C" void kernel_launch(void* const* d_in, const int* in_sizes, int n_in,
                              void* d_out, int out_size, void* d_ws, size_t ws_size,
                              hipStream_t stream) {
    const float* x   = (const float*)d_in[0];
    const float* rw  = (const float*)d_in[1];
    const float* w1  = (const float*)d_in[2];
    const float* b1  = (const float*)d_in[3];
    const float* w2  = (const float*)d_in[4];
    const float* b2  = (const float*)d_in[5];
    float* out = (float*)d_out;

    const size_t HCAP = (size_t)PCAP_ * F_;
    const size_t XCAP = (size_t)PCAP_ * D_;
    const size_t WCAP = (size_t)E_ * D_ * F_;
    const size_t misc = ((size_t)T_ * E_ + T_ + (size_t)E_ * T_) * 4 + 256;

    const size_t need_A = (2 * HCAP + 2 * XCAP + 2 * WCAP) * 2 + misc;   // ~246 MB
    const size_t hf = (size_t)T_ * F_;
    const size_t xd = (size_t)T_ * D_;
    const size_t need_B = (2 * hf + 2 * xd + 2 * WCAP) * 2 + misc;       // ~201 MB

    if (ws_size >= need_A) {
        ushort_t* hh  = (ushort_t*)d_ws;
        ushort_t* hl  = hh + HCAP;
        ushort_t* xh  = hl + HCAP;
        ushort_t* xl  = xh + XCAP;
        ushort_t* wph = xl + XCAP;
        ushort_t* wpl = wph + WCAP;
        float* r    = (float*)(wpl + WCAP);
        float* gate = r + (size_t)T_ * E_;
        int* list   = (int*)(gate + T_);
        int* counts = list + (size_t)E_ * T_;
        int* offs   = counts + E_;
        int* pbase  = offs + E_;

        k_router<<<T_ / 4, 256, 0, stream>>>(x, rw, r, counts);
        k_convert_w<<<dim3(F_ / 128, D_ / 32, E_), 256, 0, stream>>>(w1, wph, wpl, D_, F_);
        k_scan<<<B_ * E_, 64, 0, stream>>>(r);
        k_route<<<T_ / 256, 256, 0, stream>>>(r, gate, list, counts);
        k_offs<<<1, 64, 0, stream>>>(counts, offs, pbase);
        k_gather<<<GCAP_, 256, 0, stream>>>(x, list, counts, pbase, xh, xl);

        k_g4<0><<<dim3(T_ / 128, F_ / 128, E_), 256, 0, stream>>>(
            xh, xl, wph, wpl, b1, nullptr, hh, hl, list, counts, pbase, nullptr);
        k_convert_w<<<dim3(D_ / 128, F_ / 32, E_), 256, 0, stream>>>(w2, wph, wpl, F_, D_);
        k_g4<1><<<dim3(T_ / 128, D_ / 128, E_), 256, 0, stream>>>(
            hh, hl, wph, wpl, b2, out, nullptr, nullptr, list, counts, pbase, gate);
    } else if (ws_size >= need_B) {
        ushort_t* hh  = (ushort_t*)d_ws;
        ushort_t* hl  = hh + hf;
        ushort_t* xh  = hl + hf;
        ushort_t* xl  = xh + xd;
        ushort_t* wph = xl + xd;
        ushort_t* wpl = wph + WCAP;
        float* r    = (float*)(wpl + WCAP);
        float* gate = r + (size_t)T_ * E_;
        int* list   = (int*)(gate + T_);
        int* counts = list + (size_t)E_ * T_;
        int* offs   = counts + E_;
        int* pbase  = offs + E_;

        k_router<<<T_ / 4, 256, 0, stream>>>(x, rw, r, counts);
        k_convert_x<<<(int)(xd / 2048), 256, 0, stream>>>(x, xh, xl);
        k_convert_w<<<dim3(F_ / 128, D_ / 32, E_), 256, 0, stream>>>(w1, wph, wpl, D_, F_);
        k_scan<<<B_ * E_, 64, 0, stream>>>(r);
        k_route<<<T_ / 256, 256, 0, stream>>>(r, gate, list, counts);
        k_offs<<<1, 64, 0, stream>>>(counts, offs, pbase);

        k_gemm2<0><<<dim3(T_ / 128, F_ / 128, E_), 256, 0, stream>>>(
            xh, xl, wph, wpl, b1, nullptr, hh, hl, list, counts, offs, nullptr,
            D_, F_, F_ / 16);
        k_convert_w<<<dim3(D_ / 128, F_ / 32, E_), 256, 0, stream>>>(w2, wph, wpl, F_, D_);
        k_gemm2<1><<<dim3(T_ / 128, D_ / 128, E_), 256, 0, stream>>>(
            hh, hl, wph, wpl, b2, out, nullptr, nullptr, list, counts, offs, gate,
            F_, D_, D_ / 16);
    }
    // else: ws too small -> leave poison, fail loudly
}